// Round 1
// baseline (2265.618 us; speedup 1.0000x reference)
//
#include <hip/hip_runtime.h>
#include <hip/hip_bf16.h>
#include <stdint.h>

// GRU-D encoder, MI355X persistent-kernel implementation.
// B=256, S=200, D=64, H=512, TD=8.

typedef unsigned short u16;
typedef unsigned int   u32;
typedef unsigned long long u64;
typedef short bfrag  __attribute__((ext_vector_type(8)));  // 8 bf16 bits for MFMA A/B frag
typedef u16   u16x8  __attribute__((ext_vector_type(8)));
typedef float f32x4  __attribute__((ext_vector_type(4)));

#define NB 256
#define NS 200
#define ND 64
#define NH 512

union UQ  { u16x8 h; bfrag s; u64 u[2]; uint4 q; };
union UF2 { float f[2]; u64 u; };

__device__ __forceinline__ float b2f(u16 v){ union { float f; u32 u; } c; c.u = ((u32)v) << 16; return c.f; }
__device__ __forceinline__ u16 f2b(float f){ union { float f; u32 u; } c; c.f = f; u32 r = c.u + 0x7FFFu + ((c.u >> 16) & 1u); return (u16)(r >> 16); }
__device__ __forceinline__ float sigm(float x){ return 1.f / (1.f + __expf(-x)); }
__device__ __forceinline__ float tanh_f(float x){ return 1.f - 2.f / (1.f + __expf(2.f * x)); }

// agent-scope (coherence-point) 8B ops: cross-XCD visible without L2 inv/wb fences
__device__ __forceinline__ u64 cload64(const void* p){
  return __hip_atomic_load((const u64*)p, __ATOMIC_RELAXED, __HIP_MEMORY_SCOPE_AGENT);
}
__device__ __forceinline__ void cstore64(void* p, u64 v){
  __hip_atomic_store((u64*)p, v, __ATOMIC_RELAXED, __HIP_MEMORY_SCOPE_AGENT);
}
__device__ __forceinline__ void load8f_c(const float* p, float* f){
  UF2 w;
  w.u = cload64(p + 0); f[0]=w.f[0]; f[1]=w.f[1];
  w.u = cload64(p + 2); f[2]=w.f[0]; f[3]=w.f[1];
  w.u = cload64(p + 4); f[4]=w.f[0]; f[5]=w.f[1];
  w.u = cload64(p + 6); f[6]=w.f[0]; f[7]=w.f[1];
}
__device__ __forceinline__ void store8f_c(float* p, const float* f){
  UF2 w;
  w.f[0]=f[0]; w.f[1]=f[1]; cstore64(p + 0, w.u);
  w.f[0]=f[2]; w.f[1]=f[3]; cstore64(p + 2, w.u);
  w.f[0]=f[4]; w.f[1]=f[5]; cstore64(p + 4, w.u);
  w.f[0]=f[6]; w.f[1]=f[7]; cstore64(p + 6, w.u);
}
__device__ __forceinline__ void spin_ge(u32* f, u32 tgt){
  while (__hip_atomic_load(f, __ATOMIC_RELAXED, __HIP_MEMORY_SCOPE_AGENT) < tgt)
    __builtin_amdgcn_s_sleep(2);
}
// load 8 consecutive f32 of a weight row, round to bf16 MFMA fragment
__device__ __forceinline__ bfrag ldfrag(const float* src){
  f32x4 lo = *(const f32x4*)src;
  f32x4 hi = *(const f32x4*)(src + 4);
  UQ z;
  z.h[0]=f2b(lo[0]); z.h[1]=f2b(lo[1]); z.h[2]=f2b(lo[2]); z.h[3]=f2b(lo[3]);
  z.h[4]=f2b(hi[0]); z.h[5]=f2b(hi[1]); z.h[6]=f2b(hi[2]); z.h[7]=f2b(hi[3]);
  return z.s;
}

// ---------------- setup kernels ----------------

__global__ void transpose_k(const float* __restrict__ Wout, float* __restrict__ WT){
  int i = blockIdx.x * 256 + threadIdx.x;
  if (i < 520 * 512) { int k = i >> 9, ho = i & 511; WT[i] = Wout[ho * 520 + k]; }
}

__global__ void mean1_k(const float* __restrict__ x, const float* __restrict__ mask,
                        float* __restrict__ PX, float* __restrict__ PM){
  int s = blockIdx.x, tid = threadIdx.x;
  __shared__ float lx[256], lm[256];
  float xa = 0.f, ma = 0.f;
  for (int i = tid; i < NB * ND; i += 256) {
    int b = i >> 6, d = i & 63;
    size_t ix = ((size_t)b * NS + s) * 64 + d;
    float m = mask[ix];
    xa += m * x[ix]; ma += m;
  }
  lx[tid] = xa; lm[tid] = ma;
  __syncthreads();
  if (tid < 64) {
    PX[(size_t)s * 64 + tid] = lx[tid] + lx[tid + 64] + lx[tid + 128] + lx[tid + 192];
    PM[(size_t)s * 64 + tid] = lm[tid] + lm[tid + 64] + lm[tid + 128] + lm[tid + 192];
  }
}

__global__ void mean2_k(const float* __restrict__ PX, const float* __restrict__ PM,
                        float* __restrict__ XMEAN){
  int d = threadIdx.x;
  float sx = 0.f, sm = 0.f;
  for (int s = 0; s < NS; ++s){ sx += PX[s * 64 + d]; sm += PM[s * 64 + d]; }
  XMEAN[d] = sx / fmaxf(sm, 1.f);
}

// per-(b,d) time chains: delta scan, x_last scan, x_hat; writes [s][b][d] bf16 streams
__global__ void prep_k(const float* __restrict__ x, const float* __restrict__ mask,
                       const float* __restrict__ tc, const float* __restrict__ wdgx,
                       const float* __restrict__ bdgx, const float* __restrict__ XMEAN,
                       u16* __restrict__ XHAT, u16* __restrict__ MASKB, u16* __restrict__ DELTA){
  int g = blockIdx.x * 256 + threadIdx.x;
  int b = g >> 6, d = g & 63;
  float xmean = XMEAN[d], wx = wdgx[d], bx = bdgx[d];
  float xl = 0.f, del = 0.f, tprev = 0.f, mprev = 1.f;
  for (int s = 0; s < NS; ++s){
    float tv = tc[b * NS + s];
    float dtv = (s == 0) ? 0.f : (tv - tprev);
    tprev = tv;
    del = dtv + (1.f - mprev) * del;
    size_t ix = ((size_t)b * NS + s) * 64 + d;
    float m = mask[ix], xv = x[ix];
    float gx = __expf(-fmaxf(0.f, wx * del + bx));
    float xh = m * xv + (1.f - m) * (gx * xl + (1.f - gx) * xmean);
    size_t ox = ((size_t)s * NB + b) * 64 + d;
    XHAT[ox] = f2b(xh); MASKB[ox] = f2b(m); DELTA[ox] = f2b(del);
    xl = m * xv + (1.f - m) * xl;
    mprev = m;
  }
}

// ---------------- persistent recurrent kernel ----------------
// grid = 256 WGs (1/CU), 256 threads (4 waves).
// bid 0..191  : GEMM1  (rb = bid/12, 12 WGs per 16-row block; 48 col-strips of 32)
//               strips 0-15 -> z, 16-31 -> r, 32-47 -> sh_partial
// bid 192..255: GEMM2  (rb = (bid-192)/4; 16 col-strips of 32) + in-register gamma_h
__global__ __launch_bounds__(256, 1) void grud_rnn(
    const float* __restrict__ Um, const float* __restrict__ Wm, const float* __restrict__ Vm,
    const float* __restrict__ bv, const float* __restrict__ Wdg, const float* __restrict__ bdg,
    const u16* __restrict__ XHAT, const u16* __restrict__ MASKB, const u16* __restrict__ DELTA,
    float* __restrict__ HDEC, u16* __restrict__ RHD, float* __restrict__ ZB,
    float* __restrict__ SHP, u16* __restrict__ HALL, u32* done1, u32* done2)
{
  const int tid = threadIdx.x, lane = tid & 63, wid = tid >> 6, bid = blockIdx.x;
  __shared__ u16 panel[80 * 16 * 8];     // A-panels [kblk][m16][8] bf16 (20 KB)
  __shared__ u16 dpanel[8 * 16 * 8];     // delta panels for gamma GEMM (2 KB)
  __shared__ float xpose[4][528];        // per-wave 16x33 transpose scratch
  float* xp = xpose[wid];
  const int r = lane >> 2, cb = (lane & 3) * 8;   // epilogue row-major mapping
  const int krow = lane >> 4;

  if (bid < 192) {
    // ================= GEMM1 =================
    const int rb = bid / 12, sg = bid % 12;
    const int type = (sg < 4) ? 0 : ((sg < 8) ? 1 : 2);   // z / r / sh
    const int st = sg * 4 + wid;
    const int cglob = st * 32;
    const int m0 = rb * 16;
    const int c0 = cglob + (lane & 15);

    // register-resident B strip: Wcat[k][c] = k<512 ? U[c][k] : (k<576 ? W[c][k-512] : V[c][k-576])
    bfrag Bf[20][2];
    #pragma unroll
    for (int kk = 0; kk < 20; ++kk) {
      if (!(type == 2 && kk < 16)) {
        const int k0 = kk * 32 + krow * 8;
        #pragma unroll
        for (int t2 = 0; t2 < 2; ++t2) {
          const int c = c0 + t2 * 16;
          const float* src;
          if (k0 < 512)      src = Um + (size_t)c * 512 + k0;
          else if (k0 < 576) src = Wm + (size_t)c * 64 + (k0 - 512);
          else               src = Vm + (size_t)c * 64 + (k0 - 576);
          Bf[kk][t2] = ldfrag(src);
        }
      }
    }
    const float bias0 = bv[c0], bias1 = bv[c0 + 16];

    for (int t = 0; t < NS; ++t) {
      { // stage x_hat/mask panels (kblk 64..79) — precomputed, normal cached loads
        const int isrc = tid >> 7, row = (tid >> 3) & 15, kb8 = tid & 7;
        const u16* sp = (isrc ? MASKB : XHAT) + ((size_t)t * NB + (m0 + row)) * 64 + kb8 * 8;
        uint4 vv = *(const uint4*)sp;
        *(uint4*)&panel[(((isrc ? 72 : 64) + kb8) * 16 + row) * 8] = vv;
      }
      if (tid == 0) spin_ge(done2 + rb * 16, 4u * (u32)t);   // HDEC[t] ready, prior bufs consumed
      __syncthreads();
      if (type != 2) {  // stage h_dec (f32 -> bf16 panels, kblk 0..63)
        #pragma unroll
        for (int it = 0; it < 4; ++it) {
          const int c = it * 256 + tid;
          const int row = c >> 6, kb = c & 63;
          float f[8];
          load8f_c(HDEC + (size_t)(m0 + row) * 512 + kb * 8, f);
          UQ pv;
          #pragma unroll
          for (int j = 0; j < 8; ++j) pv.h[j] = f2b(f[j]);
          *(u16x8*)&panel[(kb * 16 + row) * 8] = pv.h;
        }
      }
      __syncthreads();
      f32x4 acc0 = {bias0, bias0, bias0, bias0};
      f32x4 acc1 = {bias1, bias1, bias1, bias1};
      #pragma unroll
      for (int kk = 0; kk < 20; ++kk) {
        if (!(type == 2 && kk < 16)) {
          bfrag a = *(const bfrag*)&panel[((kk * 4 + krow) * 16 + (lane & 15)) * 8];
          acc0 = __builtin_amdgcn_mfma_f32_16x16x32_bf16(a, Bf[kk][0], acc0, 0, 0, 0);
          acc1 = __builtin_amdgcn_mfma_f32_16x16x32_bf16(a, Bf[kk][1], acc1, 0, 0, 0);
        }
      }
      { // transpose C-frag to row-major via LDS (wave-private)
        const int r0 = krow * 4, cc = lane & 15;
        #pragma unroll
        for (int j = 0; j < 4; ++j) { xp[(r0 + j) * 33 + cc] = acc0[j]; xp[(r0 + j) * 33 + 16 + cc] = acc1[j]; }
      }
      float s8[8];
      #pragma unroll
      for (int q = 0; q < 8; ++q) s8[q] = xp[r * 33 + cb + q];
      const size_t orow = (size_t)(m0 + r) * 512;
      if (type == 0) {            // z gate (f32, feeds h_new blend)
        float zf[8];
        #pragma unroll
        for (int q = 0; q < 8; ++q) zf[q] = sigm(s8[q]);
        store8f_c(ZB + orow + cglob + cb, zf);
      } else if (type == 1) {     // r gate -> r * h_dec (bf16, next GEMM input)
        const int hc = cglob - 512 + cb;
        UQ hv; hv.h = *(const u16x8*)&panel[((hc >> 3) * 16 + r) * 8];
        UQ pv;
        #pragma unroll
        for (int q = 0; q < 8; ++q) pv.h[q] = f2b(sigm(s8[q]) * b2f(hv.h[q]));
        u16* dst = RHD + orow + hc;
        cstore64(dst, pv.u[0]); cstore64(dst + 4, pv.u[1]);
      } else {                    // sh partial: xhat@Wh + m@Vh + bh
        store8f_c(SHP + orow + (cglob - 1024) + cb, s8);
      }
      asm volatile("s_waitcnt vmcnt(0)" ::: "memory");
      __syncthreads();
      if (tid == 0) __hip_atomic_fetch_add(done1 + rb * 16, 1u, __ATOMIC_RELAXED, __HIP_MEMORY_SCOPE_AGENT);
    }
  } else {
    // ================= GEMM2 + gamma_h =================
    const int b2 = bid - 192;
    const int rb = b2 >> 2, sg = b2 & 3;
    const int st = sg * 4 + wid;
    const int n0 = st * 32;
    const int m0 = rb * 16;
    const int c0 = n0 + (lane & 15);

    bfrag Bh[16][2];
    #pragma unroll
    for (int kk = 0; kk < 16; ++kk) {
      const int k0 = kk * 32 + krow * 8;
      #pragma unroll
      for (int t2 = 0; t2 < 2; ++t2)
        Bh[kk][t2] = ldfrag(Um + (size_t)(1024 + c0 + t2 * 16) * 512 + k0);
    }
    bfrag Bg[2][2];
    #pragma unroll
    for (int kk = 0; kk < 2; ++kk) {
      const int k0 = kk * 32 + krow * 8;
      #pragma unroll
      for (int t2 = 0; t2 < 2; ++t2)
        Bg[kk][t2] = ldfrag(Wdg + (size_t)(c0 + t2 * 16) * 64 + k0);
    }
    const float gb0 = bdg[c0], gb1 = bdg[c0 + 16];

    for (int t = 0; t < NS; ++t) {
      float gam[8] = {0,0,0,0,0,0,0,0};
      if (t < NS - 1) {   // gamma_h[t+1] in-register (delta[t+1] @ Wdg^T)
        if (tid < 128) {
          const int row = (tid >> 3) & 15, kb8 = tid & 7;
          const u16* sp = DELTA + ((size_t)(t + 1) * NB + (m0 + row)) * 64 + kb8 * 8;
          *(uint4*)&dpanel[(kb8 * 16 + row) * 8] = *(const uint4*)sp;
        }
        __syncthreads();
        f32x4 g0 = {gb0, gb0, gb0, gb0};
        f32x4 g1 = {gb1, gb1, gb1, gb1};
        #pragma unroll
        for (int kk = 0; kk < 2; ++kk) {
          bfrag a = *(const bfrag*)&dpanel[((kk * 4 + krow) * 16 + (lane & 15)) * 8];
          g0 = __builtin_amdgcn_mfma_f32_16x16x32_bf16(a, Bg[kk][0], g0, 0, 0, 0);
          g1 = __builtin_amdgcn_mfma_f32_16x16x32_bf16(a, Bg[kk][1], g1, 0, 0, 0);
        }
        const int r0 = krow * 4, cc = lane & 15;
        #pragma unroll
        for (int j = 0; j < 4; ++j) { xp[(r0 + j) * 33 + cc] = g0[j]; xp[(r0 + j) * 33 + 16 + cc] = g1[j]; }
        #pragma unroll
        for (int q = 0; q < 8; ++q) gam[q] = __expf(-fmaxf(0.f, xp[r * 33 + cb + q]));
      }
      if (tid == 0) spin_ge(done1 + rb * 16, 12u * (u32)(t + 1));  // all GEMM1 of step t done
      __syncthreads();
      #pragma unroll
      for (int it = 0; it < 4; ++it) {   // stage r*h_dec panels
        const int c = it * 256 + tid;
        const int row = c >> 6, kb = c & 63;
        const u16* sp = RHD + (size_t)(m0 + row) * 512 + kb * 8;
        UQ pv; pv.u[0] = cload64(sp); pv.u[1] = cload64(sp + 4);
        *(u16x8*)&panel[(kb * 16 + row) * 8] = pv.h;
      }
      __syncthreads();
      f32x4 acc0 = {0.f, 0.f, 0.f, 0.f}, acc1 = {0.f, 0.f, 0.f, 0.f};
      #pragma unroll
      for (int kk = 0; kk < 16; ++kk) {
        bfrag a = *(const bfrag*)&panel[((kk * 4 + krow) * 16 + (lane & 15)) * 8];
        acc0 = __builtin_amdgcn_mfma_f32_16x16x32_bf16(a, Bh[kk][0], acc0, 0, 0, 0);
        acc1 = __builtin_amdgcn_mfma_f32_16x16x32_bf16(a, Bh[kk][1], acc1, 0, 0, 0);
      }
      {
        const int r0 = krow * 4, cc = lane & 15;
        #pragma unroll
        for (int j = 0; j < 4; ++j) { xp[(r0 + j) * 33 + cc] = acc0[j]; xp[(r0 + j) * 33 + 16 + cc] = acc1[j]; }
      }
      const int hc = n0 + cb;
      const size_t orow = (size_t)(m0 + r) * 512;
      float s2[8], shp[8], zz[8], hd[8], hn[8], hdn[8];
      #pragma unroll
      for (int q = 0; q < 8; ++q) s2[q] = xp[r * 33 + cb + q];
      load8f_c(SHP + orow + hc, shp);
      load8f_c(ZB + orow + hc, zz);
      load8f_c(HDEC + orow + hc, hd);
      UQ hw;
      #pragma unroll
      for (int q = 0; q < 8; ++q) {
        float til = tanh_f(shp[q] + s2[q]);
        hn[q] = (1.f - zz[q]) * hd[q] + zz[q] * til;
        hw.h[q] = f2b(hn[q]);
        hdn[q] = gam[q] * hn[q];   // h_dec for step t+1
      }
      u16* hp = HALL + ((size_t)t * NB + (m0 + r)) * 512 + hc;
      cstore64(hp, hw.u[0]); cstore64(hp + 4, hw.u[1]);
      if (t < NS - 1) store8f_c(HDEC + orow + hc, hdn);
      asm volatile("s_waitcnt vmcnt(0)" ::: "memory");
      __syncthreads();
      if (tid == 0) __hip_atomic_fetch_add(done2 + rb * 16, 1u, __ATOMIC_RELAXED, __HIP_MEMORY_SCOPE_AGENT);
    }
  }
}

// ---------------- post kernels ----------------

__global__ void attn_k(const u16* __restrict__ HALL, const float* __restrict__ av,
                       float* __restrict__ ATTN){
  const int b = blockIdx.x, tid = threadIdx.x, lane = tid & 63, wid = tid >> 6;
  __shared__ float avs[512], wgt[256], red[8];
  for (int i = tid; i < 512; i += 256) avs[i] = av[i];
  __syncthreads();
  float val = -3.0e38f;
  if (tid < NS) {
    const u16* hp = HALL + ((size_t)tid * NB + b) * 512;
    float acc = 0.f;
    for (int h = 0; h < 512; h += 8) {
      UQ w; w.q = *(const uint4*)(hp + h);
      #pragma unroll
      for (int j = 0; j < 8; ++j) acc += b2f(w.h[j]) * avs[h + j];
    }
    val = acc * 0.04419417382415922f;   // 1/sqrt(512)
  }
  float m = val;
  #pragma unroll
  for (int off = 32; off; off >>= 1) m = fmaxf(m, __shfl_xor(m, off, 64));
  if (lane == 0) red[wid] = m;
  __syncthreads();
  m = fmaxf(fmaxf(red[0], red[1]), fmaxf(red[2], red[3]));
  float e = (tid < NS) ? __expf(val - m) : 0.f;
  float sum = e;
  #pragma unroll
  for (int off = 32; off; off >>= 1) sum += __shfl_xor(sum, off, 64);
  if (lane == 0) red[4 + wid] = sum;
  __syncthreads();
  const float ssum = red[4] + red[5] + red[6] + red[7];
  wgt[tid] = e / ssum;
  __syncthreads();
  float a0 = 0.f, a1 = 0.f;
  const int h0 = tid * 2;
  for (int s = 0; s < NS; ++s) {
    float w = wgt[s];
    u32 pr = *(const u32*)(HALL + ((size_t)s * NB + b) * 512 + h0);
    a0 += w * b2f((u16)(pr & 0xFFFFu));
    a1 += w * b2f((u16)(pr >> 16));
  }
  ATTN[(size_t)b * 512 + h0] = a0;
  ATTN[(size_t)b * 512 + h0 + 1] = a1;
}

__global__ void out_k(const float* __restrict__ ATTN, const float* __restrict__ Ain,
                      const float* __restrict__ WT, const float* __restrict__ bout,
                      float* __restrict__ OUT){
  const int b = blockIdx.x, tid = threadIdx.x;
  __shared__ float ah[512], aa[8];
  for (int i = tid; i < 512; i += 256) ah[i] = ATTN[(size_t)b * 512 + i];
  if (tid < 8) aa[tid] = Ain[b * 8 + tid];
  __syncthreads();
  #pragma unroll
  for (int part = 0; part < 2; ++part) {
    const int ho = part * 256 + tid;
    float acc = bout[ho];
    #pragma unroll 8
    for (int k = 0; k < 512; ++k) acc += ah[k] * WT[(size_t)k * 512 + ho];
    #pragma unroll
    for (int k = 0; k < 8; ++k) acc += aa[k] * WT[(size_t)(512 + k) * 512 + ho];
    OUT[(size_t)b * 512 + ho] = acc;
  }
}

// ---------------- host ----------------

extern "C" void kernel_launch(void* const* d_in, const int* in_sizes, int n_in,
                              void* d_out, int out_size, void* d_ws, size_t ws_size,
                              hipStream_t stream) {
  (void)in_sizes; (void)n_in; (void)out_size; (void)ws_size;
  const float* x    = (const float*)d_in[0];
  const float* a_in = (const float*)d_in[1];
  const float* tc   = (const float*)d_in[2];
  const float* mask = (const float*)d_in[3];
  const float* wdgx = (const float*)d_in[4];
  const float* bdgx = (const float*)d_in[5];
  const float* Wdgh = (const float*)d_in[6];
  const float* bdgh = (const float*)d_in[7];
  const float* Wm   = (const float*)d_in[8];
  const float* Um   = (const float*)d_in[9];
  const float* Vm   = (const float*)d_in[10];
  const float* bvv  = (const float*)d_in[11];
  const float* attv = (const float*)d_in[12];
  const float* Wout = (const float*)d_in[13];
  const float* bout = (const float*)d_in[14];

  char* ws = (char*)d_ws;
  size_t o = 0;
  auto al = [&](size_t sz) { size_t r = o; o += (sz + 255) & ~(size_t)255; return r; };
  u32*   flags = (u32*)  (ws + al(4096));
  float* XMEAN = (float*)(ws + al(256));
  float* PX    = (float*)(ws + al((size_t)NS * 64 * 4));
  float* PM    = (float*)(ws + al((size_t)NS * 64 * 4));
  u16*   XHAT  = (u16*)  (ws + al((size_t)NS * NB * 64 * 2));
  u16*   MASKB = (u16*)  (ws + al((size_t)NS * NB * 64 * 2));
  u16*   DELTA = (u16*)  (ws + al((size_t)NS * NB * 64 * 2));
  float* HDEC  = (float*)(ws + al((size_t)NB * NH * 4));
  u16*   RHD   = (u16*)  (ws + al((size_t)NB * NH * 2));
  float* ZB    = (float*)(ws + al((size_t)NB * NH * 4));
  float* SHP   = (float*)(ws + al((size_t)NB * NH * 4));
  u16*   HALL  = (u16*)  (ws + al((size_t)NS * NB * NH * 2));
  float* ATTN  = (float*)(ws + al((size_t)NB * NH * 4));
  float* WT    = (float*)(ws + al((size_t)520 * 512 * 4));
  u32* done1 = flags;
  u32* done2 = flags + 256;

  hipMemsetAsync(flags, 0, 4096, stream);
  hipMemsetAsync(HDEC, 0, (size_t)NB * NH * 4, stream);

  transpose_k<<<(520 * 512 + 255) / 256, 256, 0, stream>>>(Wout, WT);
  mean1_k<<<NS, 256, 0, stream>>>(x, mask, PX, PM);
  mean2_k<<<1, 64, 0, stream>>>(PX, PM, XMEAN);
  prep_k<<<NB * ND / 256, 256, 0, stream>>>(x, mask, tc, wdgx, bdgx, XMEAN, XHAT, MASKB, DELTA);
  grud_rnn<<<256, 256, 0, stream>>>(Um, Wm, Vm, bvv, Wdgh, bdgh, XHAT, MASKB, DELTA,
                                    HDEC, RHD, ZB, SHP, HALL, done1, done2);
  attn_k<<<NB, 256, 0, stream>>>(HALL, attv, ATTN);
  out_k<<<NB, 256, 0, stream>>>(ATTN, a_in, WT, bout, (float*)d_out);
}